// Round 1
// baseline (406.114 us; speedup 1.0000x reference)
//
#include <hip/hip_runtime.h>
#include <cstdint>
#include <cstddef>

using half8  = __attribute__((ext_vector_type(8))) _Float16;
using half4  = __attribute__((ext_vector_type(4))) _Float16;
using float4v = __attribute__((ext_vector_type(4))) float;

#define CD 1024
#define M2 (1024 * 1024)

// ---------------------------------------------------------------------------
// Weight prep: f32 -> f16, stack Wf/Wg/Wh into one (3C x C), stack biases.
// ---------------------------------------------------------------------------
__global__ void prep_weights(const float* __restrict__ Wf, const float* __restrict__ Wg,
                             const float* __restrict__ Wh, const float* __restrict__ Wc,
                             const float* __restrict__ bf, const float* __restrict__ bg,
                             const float* __restrict__ bh,
                             _Float16* __restrict__ Wfgh, _Float16* __restrict__ WcH,
                             float* __restrict__ bstack) {
    int idx = blockIdx.x * 256 + threadIdx.x;
    if (idx < 3 * M2) {
        const float* s = idx < M2 ? Wf : (idx < 2 * M2 ? Wg : Wh);
        int off = idx & (M2 - 1);
        Wfgh[idx] = (_Float16)s[off];
    } else if (idx < 4 * M2) {
        WcH[idx - 3 * M2] = (_Float16)Wc[idx - 3 * M2];
    } else if (idx < 4 * M2 + 3 * CD) {
        int j = idx - 4 * M2;
        const float* s = j < CD ? bf : (j < 2 * CD ? bg : bh);
        bstack[j] = s[j & (CD - 1)];
    }
}

// ---------------------------------------------------------------------------
// Per-batch transpose: x[b][k][n] (f32) -> xT[z][n][k] (f16)
// ---------------------------------------------------------------------------
__global__ void transpose_x(const float* __restrict__ x, _Float16* __restrict__ xT, int b0) {
    __shared__ float tile[32][33];
    int z = blockIdx.z;
    const float* xb = x + (size_t)(b0 + z) * M2;
    _Float16* xTb = xT + (size_t)z * M2;
    int n0 = blockIdx.x * 32, k0 = blockIdx.y * 32;
    int tx = threadIdx.x, ty = threadIdx.y;  // 32 x 8
#pragma unroll
    for (int i = 0; i < 4; i++)
        tile[ty + i * 8][tx] = xb[(size_t)(k0 + ty + i * 8) * CD + n0 + tx];
    __syncthreads();
#pragma unroll
    for (int i = 0; i < 4; i++)
        xTb[(size_t)(n0 + ty + i * 8) * CD + k0 + tx] = (_Float16)tile[tx][ty + i * 8];
}

// ---------------------------------------------------------------------------
// Row softmax over ST (f32, rows are fixed d, reduce over c) -> attnT (f16)
// ---------------------------------------------------------------------------
__global__ __launch_bounds__(256) void softmax_col(const float* __restrict__ ST,
                                                   _Float16* __restrict__ attnT) {
    int d = blockIdx.x, z = blockIdx.y;
    const float* row = ST + ((size_t)z * CD + d) * CD;
    _Float16* orow = attnT + ((size_t)z * CD + d) * CD;
    int t = threadIdx.x;
    float4v v = *(const float4v*)(row + t * 4);
    float mx = fmaxf(fmaxf(v[0], v[1]), fmaxf(v[2], v[3]));
#pragma unroll
    for (int o = 32; o > 0; o >>= 1) mx = fmaxf(mx, __shfl_xor(mx, o));
    __shared__ float redm[4], reds[4];
    int wave = t >> 6, lane = t & 63;
    if (lane == 0) redm[wave] = mx;
    __syncthreads();
    mx = fmaxf(fmaxf(redm[0], redm[1]), fmaxf(redm[2], redm[3]));
    float e[4];
    float s = 0.f;
#pragma unroll
    for (int i = 0; i < 4; i++) {
        e[i] = __expf(v[i] - mx);
        s += e[i];
    }
#pragma unroll
    for (int o = 32; o > 0; o >>= 1) s += __shfl_xor(s, o);
    if (lane == 0) reds[wave] = s;
    __syncthreads();
    s = reds[0] + reds[1] + reds[2] + reds[3];
    float inv = 1.0f / s;
    half4 ov;
#pragma unroll
    for (int i = 0; i < 4; i++) ov[i] = (_Float16)(e[i] * inv);
    *(half4*)(orow + t * 4) = ov;
}

// ---------------------------------------------------------------------------
// NT GEMM: C[m][n] = sum_k A[m][k] * B[n][k]   (K = 1024, ld = 1024 for A,B)
// 128x128 tile, BK=32, 4 waves (2x2), mfma_f32_16x16x32_f16.
// Epilogues: 0 = f16 + row bias, 1 = f32, 2 = f16, 3 = final (bias, leaky,
// BN eval, +x residual, f32 out).
// ---------------------------------------------------------------------------
enum { EP_F16B = 0, EP_F32 = 1, EP_F16 = 2, EP_FIN = 3 };

template <int EPI>
__global__ __launch_bounds__(256) void gemm_nt(
    const _Float16* __restrict__ A, int64_t sA, const _Float16* __restrict__ B, int64_t sB,
    void* __restrict__ Cp, int64_t sC, const float* __restrict__ bias,
    const float* __restrict__ bc, const float* __restrict__ gamma,
    const float* __restrict__ beta, const float* __restrict__ rmean,
    const float* __restrict__ rvar, const float* __restrict__ xres) {
    __shared__ __align__(16) _Float16 As[128][40];  // +8 pad: 2-way bank alias (free)
    __shared__ __align__(16) _Float16 Bs[128][40];
    int z = blockIdx.z;
    const _Float16* Ab = A + (size_t)z * sA;
    const _Float16* Bb = B + (size_t)z * sB;
    int row0 = blockIdx.y * 128, col0 = blockIdx.x * 128;
    int tid = threadIdx.x, lane = tid & 63, wave = tid >> 6;
    int wr = wave >> 1, wc = wave & 1;
    float4v acc[4][4] = {};
    for (int kt = 0; kt < 1024; kt += 32) {
#pragma unroll
        for (int i = 0; i < 2; i++) {
            int c = tid + i * 256;
            int r = c >> 2, kc = (c & 3) * 8;
            *(half8*)(&As[r][kc]) = *(const half8*)(Ab + (size_t)(row0 + r) * 1024 + kt + kc);
            *(half8*)(&Bs[r][kc]) = *(const half8*)(Bb + (size_t)(col0 + r) * 1024 + kt + kc);
        }
        __syncthreads();
        half8 af[4], bfr[4];
        int kq = (lane >> 4) * 8, rl = lane & 15;
#pragma unroll
        for (int m = 0; m < 4; m++) af[m] = *(const half8*)(&As[wr * 64 + m * 16 + rl][kq]);
#pragma unroll
        for (int n = 0; n < 4; n++) bfr[n] = *(const half8*)(&Bs[wc * 64 + n * 16 + rl][kq]);
#pragma unroll
        for (int m = 0; m < 4; m++)
#pragma unroll
            for (int n = 0; n < 4; n++)
                acc[m][n] = __builtin_amdgcn_mfma_f32_16x16x32_f16(af[m], bfr[n], acc[m][n], 0, 0, 0);
        __syncthreads();
    }
    // Epilogue. C/D layout: col = lane&15, row = (lane>>4)*4 + reg  [m89-verified]
#pragma unroll
    for (int m = 0; m < 4; m++) {
#pragma unroll
        for (int r = 0; r < 4; r++) {
            int row = row0 + wr * 64 + m * 16 + ((lane >> 4) << 2) + r;
            float add0 = 0.f, mu = 0.f, invs = 1.f, bet = 0.f;
            if constexpr (EPI == EP_F16B) add0 = bias[row];
            if constexpr (EPI == EP_FIN) {
                add0 = bc[row];
                mu = rmean[row];
                invs = gamma[row] * rsqrtf(rvar[row] + 1e-5f);
                bet = beta[row];
            }
#pragma unroll
            for (int n = 0; n < 4; n++) {
                int col = col0 + wc * 64 + n * 16 + (lane & 15);
                float v = acc[m][n][r];
                if constexpr (EPI == EP_F16B) {
                    ((_Float16*)Cp)[(size_t)z * sC + (size_t)row * 1024 + col] = (_Float16)(v + add0);
                } else if constexpr (EPI == EP_F32) {
                    ((float*)Cp)[(size_t)z * sC + (size_t)row * 1024 + col] = v;
                } else if constexpr (EPI == EP_F16) {
                    ((_Float16*)Cp)[(size_t)z * sC + (size_t)row * 1024 + col] = (_Float16)v;
                } else {
                    v += add0;
                    v = v >= 0.f ? v : 0.01f * v;
                    v = (v - mu) * invs + bet;
                    v += xres[(size_t)z * M2 + (size_t)row * 1024 + col];
                    ((float*)Cp)[(size_t)z * sC + (size_t)row * 1024 + col] = v;
                }
            }
        }
    }
}

// ---------------------------------------------------------------------------
extern "C" void kernel_launch(void* const* d_in, const int* in_sizes, int n_in,
                              void* d_out, int out_size, void* d_ws, size_t ws_size,
                              hipStream_t stream) {
    const float* x = (const float*)d_in[0];
    const float* Wf = (const float*)d_in[1];
    const float* bf = (const float*)d_in[2];
    const float* Wg = (const float*)d_in[3];
    const float* bg = (const float*)d_in[4];
    const float* Wh = (const float*)d_in[5];
    const float* bh = (const float*)d_in[6];
    const float* Wc = (const float*)d_in[7];
    const float* bc = (const float*)d_in[8];
    const float* gamma = (const float*)d_in[9];
    const float* beta = (const float*)d_in[10];
    const float* rmean = (const float*)d_in[11];
    const float* rvar = (const float*)d_in[12];

    // Fixed ws region: Wfgh f16 (6MB) + Wc f16 (2MB) + bias stack
    char* p = (char*)d_ws;
    _Float16* Wfgh = (_Float16*)p;
    p += (size_t)3 * M2 * 2;
    _Float16* WcH = (_Float16*)p;
    p += (size_t)M2 * 2;
    float* bstack = (float*)p;
    p += (size_t)3 * CD * 4;
    size_t fixed = (size_t)(p - (char*)d_ws);
    fixed = (fixed + 255) & ~(size_t)255;

    // Per-batch region: xT f16 (2MB, reused as attnT) + FGH f16 (6MB) +
    // ST f32 (4MB, reused as hfgT f16). 12 MiB per batch.
    size_t perB = (size_t)2 * M2 + (size_t)6 * M2 + (size_t)4 * M2;
    int nb = 16;
    while (nb > 1 && fixed + (size_t)nb * perB > ws_size) nb >>= 1;

    {
        int total = 4 * M2 + 3 * CD;
        prep_weights<<<dim3((total + 255) / 256), dim3(256), 0, stream>>>(
            Wf, Wg, Wh, Wc, bf, bg, bh, Wfgh, WcH, bstack);
    }

    for (int b0 = 0; b0 < 16; b0 += nb) {
        char* q = (char*)d_ws + fixed;
        _Float16* xT = (_Float16*)q;
        _Float16* FGH = (_Float16*)(q + (size_t)nb * 2 * M2);
        float* ST = (float*)(q + (size_t)nb * 8 * M2);
        _Float16* attnT = xT;          // xT dead after GEMM1
        _Float16* hfgT = (_Float16*)ST;  // ST dead after softmax

        // xT[z][n][k] = x[b0+z][k][n]
        transpose_x<<<dim3(32, 32, nb), dim3(32, 8), 0, stream>>>(x, xT, b0);
        // FGH[z] (3072 x 1024) = Wfgh (3072x1024) . xT[z]^T  + bias
        gemm_nt<EP_F16B><<<dim3(8, 24, nb), dim3(256), 0, stream>>>(
            Wfgh, 0, xT, M2, FGH, (int64_t)3 * M2, bstack,
            nullptr, nullptr, nullptr, nullptr, nullptr, nullptr);
        // ST[z][d][c] = sum_n G[d][n] F[c][n]
        gemm_nt<EP_F32><<<dim3(8, 8, nb), dim3(256), 0, stream>>>(
            FGH + M2, (int64_t)3 * M2, FGH, (int64_t)3 * M2, ST, M2,
            nullptr, nullptr, nullptr, nullptr, nullptr, nullptr, nullptr);
        // attnT[z][d][c] = softmax over c of ST[z][d][:]
        softmax_col<<<dim3(1024, nb), dim3(256), 0, stream>>>(ST, attnT);
        // hfgT[z][d][c] = sum_n attnT[d][n] H[c][n]
        gemm_nt<EP_F16><<<dim3(8, 8, nb), dim3(256), 0, stream>>>(
            attnT, M2, FGH + 2 * M2, (int64_t)3 * M2, hfgT, M2,
            nullptr, nullptr, nullptr, nullptr, nullptr, nullptr, nullptr);
        // out[b][o][d] = BN(leaky(Wc . hfgT^T + bc)) + x
        gemm_nt<EP_FIN><<<dim3(8, 8, nb), dim3(256), 0, stream>>>(
            WcH, 0, hfgT, M2, (float*)d_out + (size_t)b0 * M2, M2,
            nullptr, bc, gamma, beta, rmean, rvar, x + (size_t)b0 * M2);
    }
}

// Round 2
// 372.216 us; speedup vs baseline: 1.0911x; 1.0911x over previous
//
#include <hip/hip_runtime.h>
#include <cstdint>
#include <cstddef>

using half8  = __attribute__((ext_vector_type(8))) _Float16;
using half4  = __attribute__((ext_vector_type(4))) _Float16;
using float4v = __attribute__((ext_vector_type(4))) float;

#define CD 1024
#define M2 (1024 * 1024)

// async global->LDS, 16B per lane, wave-uniform LDS base + lane*16 dest
#define GLD16(gp, lp)                                                          \
    __builtin_amdgcn_global_load_lds(                                          \
        (const __attribute__((address_space(1))) void*)(gp),                   \
        (__attribute__((address_space(3))) void*)(lp), 16, 0, 0)

// ---------------------------------------------------------------------------
// Weight prep: f32 -> f16, stack Wf/Wg/Wh into one (3C x C), stack biases.
// ---------------------------------------------------------------------------
__global__ void prep_weights(const float* __restrict__ Wf, const float* __restrict__ Wg,
                             const float* __restrict__ Wh, const float* __restrict__ Wc,
                             const float* __restrict__ bf, const float* __restrict__ bg,
                             const float* __restrict__ bh,
                             _Float16* __restrict__ Wfgh, _Float16* __restrict__ WcH,
                             float* __restrict__ bstack) {
    int idx = blockIdx.x * 256 + threadIdx.x;
    if (idx < 3 * M2) {
        const float* s = idx < M2 ? Wf : (idx < 2 * M2 ? Wg : Wh);
        int off = idx & (M2 - 1);
        Wfgh[idx] = (_Float16)s[off];
    } else if (idx < 4 * M2) {
        WcH[idx - 3 * M2] = (_Float16)Wc[idx - 3 * M2];
    } else if (idx < 4 * M2 + 3 * CD) {
        int j = idx - 4 * M2;
        const float* s = j < CD ? bf : (j < 2 * CD ? bg : bh);
        bstack[j] = s[j & (CD - 1)];
    }
}

// ---------------------------------------------------------------------------
// Per-batch transpose: x[b][k][n] (f32) -> xT[z][n][k] (f16)
// ---------------------------------------------------------------------------
__global__ void transpose_x(const float* __restrict__ x, _Float16* __restrict__ xT, int b0) {
    __shared__ float tile[32][33];
    int z = blockIdx.z;
    const float* xb = x + (size_t)(b0 + z) * M2;
    _Float16* xTb = xT + (size_t)z * M2;
    int n0 = blockIdx.x * 32, k0 = blockIdx.y * 32;
    int tx = threadIdx.x, ty = threadIdx.y;  // 32 x 8
#pragma unroll
    for (int i = 0; i < 4; i++)
        tile[ty + i * 8][tx] = xb[(size_t)(k0 + ty + i * 8) * CD + n0 + tx];
    __syncthreads();
#pragma unroll
    for (int i = 0; i < 4; i++)
        xTb[(size_t)(n0 + ty + i * 8) * CD + k0 + tx] = (_Float16)tile[tx][ty + i * 8];
}

// ---------------------------------------------------------------------------
// Row softmax over ST (f32, rows are fixed d, reduce over c) -> attnT (f16)
// ---------------------------------------------------------------------------
__global__ __launch_bounds__(256) void softmax_col(const float* __restrict__ ST,
                                                   _Float16* __restrict__ attnT) {
    int d = blockIdx.x, z = blockIdx.y;
    const float* row = ST + ((size_t)z * CD + d) * CD;
    _Float16* orow = attnT + ((size_t)z * CD + d) * CD;
    int t = threadIdx.x;
    float4v v = *(const float4v*)(row + t * 4);
    float mx = fmaxf(fmaxf(v[0], v[1]), fmaxf(v[2], v[3]));
#pragma unroll
    for (int o = 32; o > 0; o >>= 1) mx = fmaxf(mx, __shfl_xor(mx, o));
    __shared__ float redm[4], reds[4];
    int wave = t >> 6, lane = t & 63;
    if (lane == 0) redm[wave] = mx;
    __syncthreads();
    mx = fmaxf(fmaxf(redm[0], redm[1]), fmaxf(redm[2], redm[3]));
    float e[4];
    float s = 0.f;
#pragma unroll
    for (int i = 0; i < 4; i++) {
        e[i] = __expf(v[i] - mx);
        s += e[i];
    }
#pragma unroll
    for (int o = 32; o > 0; o >>= 1) s += __shfl_xor(s, o);
    if (lane == 0) reds[wave] = s;
    __syncthreads();
    s = reds[0] + reds[1] + reds[2] + reds[3];
    float inv = 1.0f / s;
    half4 ov;
#pragma unroll
    for (int i = 0; i < 4; i++) ov[i] = (_Float16)(e[i] * inv);
    *(half4*)(orow + t * 4) = ov;
}

// ---------------------------------------------------------------------------
// NT GEMM, m97 structure: C[m][n] = sum_k A[m][k] * B[n][k]  (K=1024, ld=1024)
// 128x128 tile, BK=32, 4 waves (2x2), mfma_f32_16x16x32_f16,
// global_load_lds width=16 staging into LINEAR [128][32] LDS (no padding:
// gload_lds dest is wave-uniform base + lane*16).
// Epilogues: 0 = f16 + row bias, 1 = f32, 2 = f16, 3 = final (bias, leaky,
// BN eval, +x residual, f32 out).
// ---------------------------------------------------------------------------
enum { EP_F16B = 0, EP_F32 = 1, EP_F16 = 2, EP_FIN = 3 };

template <int EPI>
__global__ __launch_bounds__(256) void gemm_nt(
    const _Float16* __restrict__ A, int64_t sA, const _Float16* __restrict__ B, int64_t sB,
    void* __restrict__ Cp, int64_t sC, const float* __restrict__ bias,
    const float* __restrict__ bc, const float* __restrict__ gamma,
    const float* __restrict__ beta, const float* __restrict__ rmean,
    const float* __restrict__ rvar, const float* __restrict__ xres) {
    __shared__ __align__(16) _Float16 As[128][32];
    __shared__ __align__(16) _Float16 Bs[128][32];
    int z = blockIdx.z;
    const _Float16* Ab = A + (size_t)z * sA;
    const _Float16* Bb = B + (size_t)z * sB;
    int row0 = blockIdx.y * 128, col0 = blockIdx.x * 128;
    int tid = threadIdx.x, lane = tid & 63, wave = tid >> 6;
    int wr = wave >> 1, wc = wave & 1;

    // Staging: wave w, issue i covers LDS rows [i*64 + w*16, +16);
    // lane l -> row + (l>>2), halves (l&3)*8. Linear in lane order. [m97]
    const int srow = lane >> 2;
    const int scol = (lane & 3) * 8;
    const size_t gA0 = (size_t)(row0 + wave * 16 + srow) * 1024 + scol;
    const size_t gA1 = gA0 + (size_t)64 * 1024;
    const size_t gB0 = (size_t)(col0 + wave * 16 + srow) * 1024 + scol;
    const size_t gB1 = gB0 + (size_t)64 * 1024;
    _Float16* ldsA0 = &As[wave * 16][0];
    _Float16* ldsA1 = &As[64 + wave * 16][0];
    _Float16* ldsB0 = &Bs[wave * 16][0];
    _Float16* ldsB1 = &Bs[64 + wave * 16][0];

    float4v acc[4][4] = {};
    const int kq = (lane >> 4) * 8, rl = lane & 15;
    for (int kt = 0; kt < 1024; kt += 32) {
        GLD16(Ab + gA0 + kt, ldsA0);
        GLD16(Ab + gA1 + kt, ldsA1);
        GLD16(Bb + gB0 + kt, ldsB0);
        GLD16(Bb + gB1 + kt, ldsB1);
        __syncthreads();
        half8 af[4], bfr[4];
#pragma unroll
        for (int m = 0; m < 4; m++) af[m] = *(const half8*)(&As[wr * 64 + m * 16 + rl][kq]);
#pragma unroll
        for (int n = 0; n < 4; n++) bfr[n] = *(const half8*)(&Bs[wc * 64 + n * 16 + rl][kq]);
#pragma unroll
        for (int m = 0; m < 4; m++)
#pragma unroll
            for (int n = 0; n < 4; n++)
                acc[m][n] = __builtin_amdgcn_mfma_f32_16x16x32_f16(af[m], bfr[n], acc[m][n], 0, 0, 0);
        __syncthreads();
    }
    // Epilogue. C/D layout: col = lane&15, row = (lane>>4)*4 + reg  [m89-verified]
#pragma unroll
    for (int m = 0; m < 4; m++) {
#pragma unroll
        for (int r = 0; r < 4; r++) {
            int row = row0 + wr * 64 + m * 16 + ((lane >> 4) << 2) + r;
            float add0 = 0.f, mu = 0.f, invs = 1.f, bet = 0.f;
            if constexpr (EPI == EP_F16B) add0 = bias[row];
            if constexpr (EPI == EP_FIN) {
                add0 = bc[row];
                mu = rmean[row];
                invs = gamma[row] * rsqrtf(rvar[row] + 1e-5f);
                bet = beta[row];
            }
#pragma unroll
            for (int n = 0; n < 4; n++) {
                int col = col0 + wc * 64 + n * 16 + (lane & 15);
                float v = acc[m][n][r];
                if constexpr (EPI == EP_F16B) {
                    ((_Float16*)Cp)[(size_t)z * sC + (size_t)row * 1024 + col] = (_Float16)(v + add0);
                } else if constexpr (EPI == EP_F32) {
                    ((float*)Cp)[(size_t)z * sC + (size_t)row * 1024 + col] = v;
                } else if constexpr (EPI == EP_F16) {
                    ((_Float16*)Cp)[(size_t)z * sC + (size_t)row * 1024 + col] = (_Float16)v;
                } else {
                    v += add0;
                    v = v >= 0.f ? v : 0.01f * v;
                    v = (v - mu) * invs + bet;
                    v += xres[(size_t)z * M2 + (size_t)row * 1024 + col];
                    ((float*)Cp)[(size_t)z * sC + (size_t)row * 1024 + col] = v;
                }
            }
        }
    }
}

// ---------------------------------------------------------------------------
extern "C" void kernel_launch(void* const* d_in, const int* in_sizes, int n_in,
                              void* d_out, int out_size, void* d_ws, size_t ws_size,
                              hipStream_t stream) {
    const float* x = (const float*)d_in[0];
    const float* Wf = (const float*)d_in[1];
    const float* bf = (const float*)d_in[2];
    const float* Wg = (const float*)d_in[3];
    const float* bg = (const float*)d_in[4];
    const float* Wh = (const float*)d_in[5];
    const float* bh = (const float*)d_in[6];
    const float* Wc = (const float*)d_in[7];
    const float* bc = (const float*)d_in[8];
    const float* gamma = (const float*)d_in[9];
    const float* beta = (const float*)d_in[10];
    const float* rmean = (const float*)d_in[11];
    const float* rvar = (const float*)d_in[12];

    // Fixed ws region: Wfgh f16 (6MB) + Wc f16 (2MB) + bias stack
    char* p = (char*)d_ws;
    _Float16* Wfgh = (_Float16*)p;
    p += (size_t)3 * M2 * 2;
    _Float16* WcH = (_Float16*)p;
    p += (size_t)M2 * 2;
    float* bstack = (float*)p;
    p += (size_t)3 * CD * 4;
    size_t fixed = (size_t)(p - (char*)d_ws);
    fixed = (fixed + 255) & ~(size_t)255;

    // Per-batch region: xT f16 (2MB, reused as attnT) + FGH f16 (6MB) +
    // ST f32 (4MB, reused as hfgT f16). 12 MiB per batch.
    size_t perB = (size_t)2 * M2 + (size_t)6 * M2 + (size_t)4 * M2;
    int nb = 16;
    while (nb > 1 && fixed + (size_t)nb * perB > ws_size) nb >>= 1;

    {
        int total = 4 * M2 + 3 * CD;
        prep_weights<<<dim3((total + 255) / 256), dim3(256), 0, stream>>>(
            Wf, Wg, Wh, Wc, bf, bg, bh, Wfgh, WcH, bstack);
    }

    for (int b0 = 0; b0 < 16; b0 += nb) {
        char* q = (char*)d_ws + fixed;
        _Float16* xT = (_Float16*)q;
        _Float16* FGH = (_Float16*)(q + (size_t)nb * 2 * M2);
        float* ST = (float*)(q + (size_t)nb * 8 * M2);
        _Float16* attnT = xT;          // xT dead after GEMM1
        _Float16* hfgT = (_Float16*)ST;  // ST dead after softmax

        // xT[z][n][k] = x[b0+z][k][n]
        transpose_x<<<dim3(32, 32, nb), dim3(32, 8), 0, stream>>>(x, xT, b0);
        // FGH[z] (3072 x 1024) = Wfgh (3072x1024) . xT[z]^T  + bias
        gemm_nt<EP_F16B><<<dim3(8, 24, nb), dim3(256), 0, stream>>>(
            Wfgh, 0, xT, M2, FGH, (int64_t)3 * M2, bstack,
            nullptr, nullptr, nullptr, nullptr, nullptr, nullptr);
        // ST[z][d][c] = sum_n G[d][n] F[c][n]
        gemm_nt<EP_F32><<<dim3(8, 8, nb), dim3(256), 0, stream>>>(
            FGH + M2, (int64_t)3 * M2, FGH, (int64_t)3 * M2, ST, M2,
            nullptr, nullptr, nullptr, nullptr, nullptr, nullptr, nullptr);
        // attnT[z][d][c] = softmax over c of ST[z][d][:]
        softmax_col<<<dim3(1024, nb), dim3(256), 0, stream>>>(ST, attnT);
        // hfgT[z][d][c] = sum_n attnT[d][n] H[c][n]
        gemm_nt<EP_F16><<<dim3(8, 8, nb), dim3(256), 0, stream>>>(
            attnT, M2, FGH + 2 * M2, (int64_t)3 * M2, hfgT, M2,
            nullptr, nullptr, nullptr, nullptr, nullptr, nullptr, nullptr);
        // out[b][o][d] = BN(leaky(Wc . hfgT^T + bc)) + x
        gemm_nt<EP_FIN><<<dim3(8, 8, nb), dim3(256), 0, stream>>>(
            WcH, 0, hfgT, M2, (float*)d_out + (size_t)b0 * M2, M2,
            nullptr, bc, gamma, beta, rmean, rvar, x + (size_t)b0 * M2);
    }
}

// Round 3
// 345.576 us; speedup vs baseline: 1.1752x; 1.0771x over previous
//
#include <hip/hip_runtime.h>
#include <cstdint>
#include <cstddef>

using half8  = __attribute__((ext_vector_type(8))) _Float16;
using half4  = __attribute__((ext_vector_type(4))) _Float16;
using float4v = __attribute__((ext_vector_type(4))) float;

#define CD 1024
#define M2 (1024 * 1024)

// async global->LDS, 16B per lane, wave-uniform LDS base + lane*16 dest
#define GLD16(gp, lp)                                                          \
    __builtin_amdgcn_global_load_lds(                                          \
        (const __attribute__((address_space(1))) void*)(gp),                   \
        (__attribute__((address_space(3))) void*)(lp), 16, 0, 0)

// ---------------------------------------------------------------------------
// Weight prep: f32 -> f16, stack Wf/Wg/Wh into one (3C x C), stack biases.
// ---------------------------------------------------------------------------
__global__ void prep_weights(const float* __restrict__ Wf, const float* __restrict__ Wg,
                             const float* __restrict__ Wh, const float* __restrict__ Wc,
                             const float* __restrict__ bf, const float* __restrict__ bg,
                             const float* __restrict__ bh,
                             _Float16* __restrict__ Wfgh, _Float16* __restrict__ WcH,
                             float* __restrict__ bstack) {
    int idx = blockIdx.x * 256 + threadIdx.x;
    if (idx < 3 * M2) {
        const float* s = idx < M2 ? Wf : (idx < 2 * M2 ? Wg : Wh);
        int off = idx & (M2 - 1);
        Wfgh[idx] = (_Float16)s[off];
    } else if (idx < 4 * M2) {
        WcH[idx - 3 * M2] = (_Float16)Wc[idx - 3 * M2];
    } else if (idx < 4 * M2 + 3 * CD) {
        int j = idx - 4 * M2;
        const float* s = j < CD ? bf : (j < 2 * CD ? bg : bh);
        bstack[j] = s[j & (CD - 1)];
    }
}

// ---------------------------------------------------------------------------
// Per-batch transpose: x[b][k][n] (f32) -> xT[z][n][k] (f16)
// ---------------------------------------------------------------------------
__global__ void transpose_x(const float* __restrict__ x, _Float16* __restrict__ xT, int b0) {
    __shared__ float tile[32][33];
    int z = blockIdx.z;
    const float* xb = x + (size_t)(b0 + z) * M2;
    _Float16* xTb = xT + (size_t)z * M2;
    int n0 = blockIdx.x * 32, k0 = blockIdx.y * 32;
    int tx = threadIdx.x, ty = threadIdx.y;  // 32 x 8
#pragma unroll
    for (int i = 0; i < 4; i++)
        tile[ty + i * 8][tx] = xb[(size_t)(k0 + ty + i * 8) * CD + n0 + tx];
    __syncthreads();
#pragma unroll
    for (int i = 0; i < 4; i++)
        xTb[(size_t)(n0 + ty + i * 8) * CD + k0 + tx] = (_Float16)tile[tx][ty + i * 8];
}

// ---------------------------------------------------------------------------
// Row softmax over ST (f32, rows are fixed d, reduce over c) -> attnT (f16)
// ---------------------------------------------------------------------------
__global__ __launch_bounds__(256) void softmax_col(const float* __restrict__ ST,
                                                   _Float16* __restrict__ attnT) {
    int d = blockIdx.x, z = blockIdx.y;
    const float* row = ST + ((size_t)z * CD + d) * CD;
    _Float16* orow = attnT + ((size_t)z * CD + d) * CD;
    int t = threadIdx.x;
    float4v v = *(const float4v*)(row + t * 4);
    float mx = fmaxf(fmaxf(v[0], v[1]), fmaxf(v[2], v[3]));
#pragma unroll
    for (int o = 32; o > 0; o >>= 1) mx = fmaxf(mx, __shfl_xor(mx, o));
    __shared__ float redm[4], reds[4];
    int wave = t >> 6, lane = t & 63;
    if (lane == 0) redm[wave] = mx;
    __syncthreads();
    mx = fmaxf(fmaxf(redm[0], redm[1]), fmaxf(redm[2], redm[3]));
    float e[4];
    float s = 0.f;
#pragma unroll
    for (int i = 0; i < 4; i++) {
        e[i] = __expf(v[i] - mx);
        s += e[i];
    }
#pragma unroll
    for (int o = 32; o > 0; o >>= 1) s += __shfl_xor(s, o);
    if (lane == 0) reds[wave] = s;
    __syncthreads();
    s = reds[0] + reds[1] + reds[2] + reds[3];
    float inv = 1.0f / s;
    half4 ov;
#pragma unroll
    for (int i = 0; i < 4; i++) ov[i] = (_Float16)(e[i] * inv);
    *(half4*)(orow + t * 4) = ov;
}

// ---------------------------------------------------------------------------
// NT GEMM, 3-deep counted-vmcnt pipeline (T3/T4) + XOR-swizzled LDS (T2) +
// setprio (T5).  C[m][n] = sum_k A[m][k]*B[n][k], K=1024, BK=32, 32 K-tiles.
// 128x128 tile, 4 waves (2x2), mfma_f32_16x16x32_f16.
// LDS: 3 buffers x (A 128x32 + B 128x32) f16 = 48 KiB.
// Pipeline ledger (per thread, 4 gload_lds per K-tile):
//   prologue: stage tiles 0,1,2 (12 outstanding); vmcnt(8) -> tile0 landed.
//   iter t: ds_read buf[t%3]; lgkmcnt(0); barrier (all waves done reading);
//           stage tile t+3 into buf[t%3] (safe); MFMA (regs);
//           vmcnt(8) -> tile t+1 landed (outstanding: t+2,t+3); barrier.
//   epilogue iters: vmcnt(8),8,4,0, none.
// Swizzle (involution, flips byte bits 4-5 with row bits 1-2):
//   stage source col = ((lane&3) ^ ((lane>>3)&3))*8   (linear LDS dest)
//   read col        = kq ^ (((rl>>1)&3)<<3)
// ---------------------------------------------------------------------------
enum { EP_F16B = 0, EP_F32 = 1, EP_F16 = 2, EP_FIN = 3 };

#define STAGE(T, B)                                                            \
    GLD16(gA + (size_t)(T) * 32, &As[B][wave * 16][0]);                        \
    GLD16(gA1 + (size_t)(T) * 32, &As[B][64 + wave * 16][0]);                  \
    GLD16(gB + (size_t)(T) * 32, &Bs[B][wave * 16][0]);                        \
    GLD16(gB1 + (size_t)(T) * 32, &Bs[B][64 + wave * 16][0]);

#define KITER(T, B, DOSTAGE, ST, WAIT, VMSTR, TBAR)                            \
    {                                                                          \
        half8 af[4], bq[4];                                                    \
        _Pragma("unroll") for (int m = 0; m < 4; m++)                          \
            af[m] = *(const half8*)&As[B][wr * 64 + m * 16 + rl][kqa];         \
        _Pragma("unroll") for (int n = 0; n < 4; n++)                          \
            bq[n] = *(const half8*)&Bs[B][wc * 64 + n * 16 + rl][kqa];         \
        asm volatile("s_waitcnt lgkmcnt(0)" ::: "memory");                     \
        __builtin_amdgcn_s_barrier();                                          \
        if (DOSTAGE) { STAGE(ST, B) }                                          \
        __builtin_amdgcn_sched_barrier(0);                                     \
        __builtin_amdgcn_s_setprio(1);                                         \
        _Pragma("unroll") for (int m = 0; m < 4; m++)                          \
            _Pragma("unroll") for (int n = 0; n < 4; n++)                      \
                acc[m][n] = __builtin_amdgcn_mfma_f32_16x16x32_f16(            \
                    af[m], bq[n], acc[m][n], 0, 0, 0);                         \
        __builtin_amdgcn_s_setprio(0);                                        \
        if (WAIT) {                                                            \
            asm volatile("s_waitcnt " VMSTR ::: "memory");                     \
            __builtin_amdgcn_sched_barrier(0);                                 \
        }                                                                      \
        if (TBAR) __builtin_amdgcn_s_barrier();                                \
    }

template <int EPI>
__global__ __launch_bounds__(256) void gemm_nt(
    const _Float16* __restrict__ A, int64_t sA, const _Float16* __restrict__ B, int64_t sB,
    void* __restrict__ Cp, int64_t sC, const float* __restrict__ bias,
    const float* __restrict__ bc, const float* __restrict__ gamma,
    const float* __restrict__ beta, const float* __restrict__ rmean,
    const float* __restrict__ rvar, const float* __restrict__ xres) {
    __shared__ __align__(16) _Float16 As[3][128][32];
    __shared__ __align__(16) _Float16 Bs[3][128][32];
    int z = blockIdx.z;
    const _Float16* Ab = A + (size_t)z * sA;
    const _Float16* Bb = B + (size_t)z * sB;
    int row0 = blockIdx.y * 128, col0 = blockIdx.x * 128;
    int tid = threadIdx.x, lane = tid & 63, wave = tid >> 6;
    int wr = wave >> 1, wc = wave & 1;

    // Staging: wave w covers LDS rows [w*16,+16) (+64 for 2nd issue);
    // lane l -> row + l/4, source col pre-swizzled (LDS dest stays linear).
    const int srow = lane >> 2;
    const int scol = ((lane & 3) ^ ((lane >> 3) & 3)) * 8;
    const _Float16* gA  = Ab + (size_t)(row0 + wave * 16 + srow) * 1024 + scol;
    const _Float16* gA1 = gA + (size_t)64 * 1024;
    const _Float16* gB  = Bb + (size_t)(col0 + wave * 16 + srow) * 1024 + scol;
    const _Float16* gB1 = gB + (size_t)64 * 1024;

    // Prologue: fill 3-deep pipeline.
    STAGE(0, 0)
    STAGE(1, 1)
    STAGE(2, 2)
    asm volatile("s_waitcnt vmcnt(8)" ::: "memory");
    __builtin_amdgcn_sched_barrier(0);
    __builtin_amdgcn_s_barrier();

    float4v acc[4][4] = {};
    const int rl = lane & 15;
    const int kq = (lane >> 4) * 8;
    const int kqa = kq ^ (((rl >> 1) & 3) << 3);  // read-side swizzle

#pragma unroll 1
    for (int g = 0; g < 9; ++g) {  // t = 3g..3g+2, covers t=0..26, stages 3..29
        int t = g * 3;
        KITER(t + 0, 0, 1, t + 3, 1, "vmcnt(8)", 1)
        KITER(t + 1, 1, 1, t + 4, 1, "vmcnt(8)", 1)
        KITER(t + 2, 2, 1, t + 5, 1, "vmcnt(8)", 1)
    }
    KITER(27, 0, 1, 30, 1, "vmcnt(8)", 1)
    KITER(28, 1, 1, 31, 1, "vmcnt(8)", 1)
    KITER(29, 2, 0, 0, 1, "vmcnt(4)", 1)
    KITER(30, 0, 0, 0, 1, "vmcnt(0)", 1)
    KITER(31, 1, 0, 0, 0, "", 0)

    // Epilogue. C/D layout: col = lane&15, row = (lane>>4)*4 + reg  [m89]
#pragma unroll
    for (int m = 0; m < 4; m++) {
#pragma unroll
        for (int r = 0; r < 4; r++) {
            int row = row0 + wr * 64 + m * 16 + ((lane >> 4) << 2) + r;
            float add0 = 0.f, mu = 0.f, invs = 1.f, bet = 0.f;
            if constexpr (EPI == EP_F16B) add0 = bias[row];
            if constexpr (EPI == EP_FIN) {
                add0 = bc[row];
                mu = rmean[row];
                invs = gamma[row] * rsqrtf(rvar[row] + 1e-5f);
                bet = beta[row];
            }
#pragma unroll
            for (int n = 0; n < 4; n++) {
                int col = col0 + wc * 64 + n * 16 + (lane & 15);
                float v = acc[m][n][r];
                if constexpr (EPI == EP_F16B) {
                    ((_Float16*)Cp)[(size_t)z * sC + (size_t)row * 1024 + col] = (_Float16)(v + add0);
                } else if constexpr (EPI == EP_F32) {
                    ((float*)Cp)[(size_t)z * sC + (size_t)row * 1024 + col] = v;
                } else if constexpr (EPI == EP_F16) {
                    ((_Float16*)Cp)[(size_t)z * sC + (size_t)row * 1024 + col] = (_Float16)v;
                } else {
                    v += add0;
                    v = v >= 0.f ? v : 0.01f * v;
                    v = (v - mu) * invs + bet;
                    v += xres[(size_t)z * M2 + (size_t)row * 1024 + col];
                    ((float*)Cp)[(size_t)z * sC + (size_t)row * 1024 + col] = v;
                }
            }
        }
    }
}

// ---------------------------------------------------------------------------
extern "C" void kernel_launch(void* const* d_in, const int* in_sizes, int n_in,
                              void* d_out, int out_size, void* d_ws, size_t ws_size,
                              hipStream_t stream) {
    const float* x = (const float*)d_in[0];
    const float* Wf = (const float*)d_in[1];
    const float* bf = (const float*)d_in[2];
    const float* Wg = (const float*)d_in[3];
    const float* bg = (const float*)d_in[4];
    const float* Wh = (const float*)d_in[5];
    const float* bh = (const float*)d_in[6];
    const float* Wc = (const float*)d_in[7];
    const float* bc = (const float*)d_in[8];
    const float* gamma = (const float*)d_in[9];
    const float* beta = (const float*)d_in[10];
    const float* rmean = (const float*)d_in[11];
    const float* rvar = (const float*)d_in[12];

    // Fixed ws region: Wfgh f16 (6MB) + Wc f16 (2MB) + bias stack
    char* p = (char*)d_ws;
    _Float16* Wfgh = (_Float16*)p;
    p += (size_t)3 * M2 * 2;
    _Float16* WcH = (_Float16*)p;
    p += (size_t)M2 * 2;
    float* bstack = (float*)p;
    p += (size_t)3 * CD * 4;
    size_t fixed = (size_t)(p - (char*)d_ws);
    fixed = (fixed + 255) & ~(size_t)255;

    // Per-batch region: xT f16 (2MB, reused as attnT) + FGH f16 (6MB) +
    // ST f32 (4MB, reused as hfgT f16). 12 MiB per batch.
    size_t perB = (size_t)2 * M2 + (size_t)6 * M2 + (size_t)4 * M2;
    int nb = 16;
    while (nb > 1 && fixed + (size_t)nb * perB > ws_size) nb >>= 1;

    {
        int total = 4 * M2 + 3 * CD;
        prep_weights<<<dim3((total + 255) / 256), dim3(256), 0, stream>>>(
            Wf, Wg, Wh, Wc, bf, bg, bh, Wfgh, WcH, bstack);
    }

    for (int b0 = 0; b0 < 16; b0 += nb) {
        char* q = (char*)d_ws + fixed;
        _Float16* xT = (_Float16*)q;
        _Float16* FGH = (_Float16*)(q + (size_t)nb * 2 * M2);
        float* ST = (float*)(q + (size_t)nb * 8 * M2);
        _Float16* attnT = xT;          // xT dead after GEMM1
        _Float16* hfgT = (_Float16*)ST;  // ST dead after softmax

        // xT[z][n][k] = x[b0+z][k][n]
        transpose_x<<<dim3(32, 32, nb), dim3(32, 8), 0, stream>>>(x, xT, b0);
        // FGH[z] (3072 x 1024) = Wfgh (3072x1024) . xT[z]^T  + bias
        gemm_nt<EP_F16B><<<dim3(8, 24, nb), dim3(256), 0, stream>>>(
            Wfgh, 0, xT, M2, FGH, (int64_t)3 * M2, bstack,
            nullptr, nullptr, nullptr, nullptr, nullptr, nullptr);
        // ST[z][d][c] = sum_n G[d][n] F[c][n]
        gemm_nt<EP_F32><<<dim3(8, 8, nb), dim3(256), 0, stream>>>(
            FGH + M2, (int64_t)3 * M2, FGH, (int64_t)3 * M2, ST, M2,
            nullptr, nullptr, nullptr, nullptr, nullptr, nullptr, nullptr);
        // attnT[z][d][c] = softmax over c of ST[z][d][:]
        softmax_col<<<dim3(1024, nb), dim3(256), 0, stream>>>(ST, attnT);
        // hfgT[z][d][c] = sum_n attnT[d][n] H[c][n]
        gemm_nt<EP_F16><<<dim3(8, 8, nb), dim3(256), 0, stream>>>(
            attnT, M2, FGH + 2 * M2, (int64_t)3 * M2, hfgT, M2,
            nullptr, nullptr, nullptr, nullptr, nullptr, nullptr, nullptr);
        // out[b][o][d] = BN(leaky(Wc . hfgT^T + bc)) + x
        gemm_nt<EP_FIN><<<dim3(8, 8, nb), dim3(256), 0, stream>>>(
            WcH, 0, hfgT, M2, (float*)d_out + (size_t)b0 * M2, M2,
            nullptr, bc, gamma, beta, rmean, rvar, x + (size_t)b0 * M2);
    }
}